// Round 6
// baseline (71759.589 us; speedup 1.0000x reference)
//
#include <hip/hip_runtime.h>
#include <math.h>

#define TSTEPS  16384
#define NTAGS   1024
#define NSLOTS  32       // participating WGs, elected onto ONE XCD
#define TPB     256      // 4 compute waves, 8 rows/wave
#define NLAUNCH 2048     // shells; pigeonhole: some XCD sees >= 256 claimants
#define START_I 1022
#define STOP_I  1023
#define SLOW_START    6  // iters of pure fast polling before slow sweeps mix in
#define TROUBLE_ITERS 64 // iterations before flagging trouble / republishing
#define BADACQ_KILL   64 // acquires resolved via slow data before fastdead

// CRF forward, linear domain — R6: sc0-store/sc0-load fast ring (the untested
// scope pairing) + full-rate exact-tagged slow fallback.
//
// Scope-matrix evidence so far:
//   sc1(agent) store + sc0 load : fast never validates (R3, 107ms fallback)
//   plain(CU)  store + sc0 load : fast never validates (R5, 57ms fallback)
//   sc0(SE)    store + sc0 load : UNTESTED (R2 hung, but had no fallback)
// R6 tests the sc0/sc0 pair: SE-scope stores write through to the XCD's L2,
// SE-scope loads bypass L1 and read that L2 — the architectural pairing for
// intra-XCD producer/consumer. Every outcome remains correct:
//  - slow ring: u64 (exact_step_tag<<32 | value), agent scope, tag match is
//    exact (no aliasing); 8B atomicity prevents tearing.
//  - liveness: stuck waves (>=64 iters) set a global trouble flag and
//    republish their register-held frontier labels (t, t-1) — unconditional.
//    All waves check trouble every 16 steps -> dualstore to the slow ring.
//  - adaptivity: a wave whose acquires keep resolving via slow data
//    (badacq >= 64) goes fastdead: skips fast sweeps, permanent dualstore.
//    Worst case ~= R1 pace (~22ms), best case XCD-L2 pace (~8-10ms).
//
//   p_{t+1} = e_t . (M p_t) / max(p_t),  S += log(max(p_t))
//   alpha   = S + log( sum_i p_T[i] * exp(trans[STOP,i]) )
// Fast-ring encoding: value = sign(t)*(p+1), sign period 4; poison/stale
// never validate while anyone still polls label t.

typedef float f32x4 __attribute__((ext_vector_type(4)));
typedef unsigned long long u64_t;

static __device__ __forceinline__ float min16(const float v[16]) {
    float a = fminf(v[0],  v[1]),  b = fminf(v[2],  v[3]);
    float c = fminf(v[4],  v[5]),  d = fminf(v[6],  v[7]);
    float e = fminf(v[8],  v[9]),  f = fminf(v[10], v[11]);
    float g = fminf(v[12], v[13]), h = fminf(v[14], v[15]);
    a = fminf(a, b); c = fminf(c, d); e = fminf(e, f); g = fminf(g, h);
    return fminf(fminf(a, c), fminf(e, g));
}
static __device__ __forceinline__ float max16(const float v[16]) {
    float a = fmaxf(v[0],  v[1]),  b = fmaxf(v[2],  v[3]);
    float c = fmaxf(v[4],  v[5]),  d = fmaxf(v[6],  v[7]);
    float e = fmaxf(v[8],  v[9]),  f = fmaxf(v[10], v[11]);
    float g = fmaxf(v[12], v[13]), h = fmaxf(v[14], v[15]);
    a = fmaxf(a, b); c = fmaxf(c, d); e = fmaxf(e, f); g = fmaxf(g, h);
    return fmaxf(fmaxf(a, c), fmaxf(e, g));
}

// One fast sweep: 4x dwordx4 sc0 loads (bypass L1, served from the XCD L2).
static __device__ __forceinline__ void fast_sweep(const float* src, float w[16]) {
    f32x4 q0, q1, q2, q3;
    asm volatile(
        "global_load_dwordx4 %0, %4, off sc0\n\t"
        "global_load_dwordx4 %1, %4, off offset:1024 sc0\n\t"
        "global_load_dwordx4 %2, %4, off offset:2048 sc0\n\t"
        "global_load_dwordx4 %3, %4, off offset:3072 sc0\n\t"
        "s_waitcnt vmcnt(0)"
        : "=&v"(q0), "=&v"(q1), "=&v"(q2), "=&v"(q3)
        : "v"(src) : "memory");
    w[0]  = q0[0]; w[1]  = q0[1]; w[2]  = q0[2]; w[3]  = q0[3];
    w[4]  = q1[0]; w[5]  = q1[1]; w[6]  = q1[2]; w[7]  = q1[3];
    w[8]  = q2[0]; w[9]  = q2[1]; w[10] = q2[2]; w[11] = q2[3];
    w[12] = q3[0]; w[13] = q3[1]; w[14] = q3[2]; w[15] = q3[3];
}

static __device__ __forceinline__ u64_t packts(int tag, float raw) {
    return ((u64_t)(unsigned)tag << 32) | (u64_t)__float_as_uint(raw);
}

// Acquire validated inputs for step t (labels t).
template <bool POS>
static __device__ __forceinline__ void acquire(
        int t, int lane, const float* fsrc, const u64_t* ssrc,
        u64_t* slowring, int myrow, bool storer, float r1, float r0,
        int* trouble, bool& troubleset, bool& fastdead, int& badacq,
        float v[16])
{
    bool have = false, slowused = false;
    int iters = 0;
    #pragma unroll 1
    for (;;) {
        if (!fastdead) {
            float w[16];
            fast_sweep(fsrc, w);
            if (!have) {
                const float ext = POS ? min16(w) : max16(w);
                const bool  ok  = POS ? (ext >= 1.0f) : (ext <= -1.0f);
                if (ok) {
                    #pragma unroll
                    for (int j = 0; j < 16; ++j) v[j] = w[j];
                    have = true;
                }
            }
            if (__all(have)) break;
        }
        ++iters;
        if (fastdead || (iters >= SLOW_START && !(iters & 1))) {
            if (!have) {
                bool good = true;
                float tmp[16];
                #pragma unroll
                for (int k = 0; k < 4; ++k)
                    #pragma unroll
                    for (int j = 0; j < 4; ++j) {
                        const u64_t q = __hip_atomic_load(ssrc + 256 * k + j,
                            __ATOMIC_RELAXED, __HIP_MEMORY_SCOPE_AGENT);
                        if ((unsigned)(q >> 32) != (unsigned)t) good = false;
                        const float raw = __uint_as_float((unsigned)q);
                        tmp[4*k+j] = POS ? (raw + 1.0f) : -(raw + 1.0f);
                    }
                if (good) {
                    #pragma unroll
                    for (int j = 0; j < 16; ++j) v[j] = tmp[j];
                    have = true; slowused = true;
                }
            }
            if (__all(have)) break;
        }
        if ((iters & (TROUBLE_ITERS - 1)) == 0) {
            if (!troubleset) {
                if (lane == 0)
                    __hip_atomic_store(trouble, 1, __ATOMIC_RELAXED,
                                       __HIP_MEMORY_SCOPE_AGENT);
                troubleset = true;
            }
            if (storer) {   // republish frontier: labels t and t-1
                __hip_atomic_store(slowring + (size_t)(t & 1) * NTAGS + myrow,
                    packts(t, r1), __ATOMIC_RELAXED, __HIP_MEMORY_SCOPE_AGENT);
                __hip_atomic_store(slowring + (size_t)((t-1) & 1) * NTAGS + myrow,
                    packts(t-1, r0), __ATOMIC_RELAXED, __HIP_MEMORY_SCOPE_AGENT);
            }
        }
    }
    // adaptivity: repeated slow-resolved acquires -> fast path is dead
    if (!fastdead) {
        if (__any(slowused)) { if (++badacq >= BADACQ_KILL) fastdead = true; }
        else if (badacq > 0) --badacq;
    }
}

// Sum 8 accumulators over 64 lanes; lane ends with sum for index (lane>>3).
static __device__ __forceinline__ float reduce8(float a[8], int lane) {
    #pragma unroll
    for (int i = 0; i < 8; ++i) a[i] += __shfl_xor(a[i], 32, 64);
    float g0 = (lane & 32) ? a[4] : a[0];
    float g1 = (lane & 32) ? a[5] : a[1];
    float g2 = (lane & 32) ? a[6] : a[2];
    float g3 = (lane & 32) ? a[7] : a[3];
    g0 += __shfl_xor(g0, 16, 64); g1 += __shfl_xor(g1, 16, 64);
    g2 += __shfl_xor(g2, 16, 64); g3 += __shfl_xor(g3, 16, 64);
    float h0 = (lane & 16) ? g2 : g0;
    float h1 = (lane & 16) ? g3 : g1;
    h0 += __shfl_xor(h0, 8, 64); h1 += __shfl_xor(h1, 8, 64);
    float b = (lane & 8) ? h1 : h0;
    b += __shfl_xor(b, 4, 64);
    b += __shfl_xor(b, 2, 64);
    b += __shfl_xor(b, 1, 64);
    return b;
}

__global__ __launch_bounds__(TPB, 1)
void crf_forward_kernel(const float* __restrict__ decoded,
                        const float* __restrict__ trans,
                        float* __restrict__ out,
                        float* __restrict__ ws)
{
    float* fastring = ws;                       // [2][1024] f32, sc0-store
    u64_t* slowring = (u64_t*)(ws + 2 * NTAGS); // [2][1024] u64, agent-scope
    int*   ibase    = (int*)(ws + 6 * NTAGS);   // cnt[8], ready, trouble, winner
    int*   cnt      = ibase;
    int*   ready    = ibase + 8;
    int*   trouble  = ibase + 9;
    int*   winner   = ibase + 10;

    __shared__ int s_slot;
    const int tid = threadIdx.x;
    if (tid == 0) {
        unsigned xcc = (unsigned)__builtin_amdgcn_s_getreg((31u << 11) | 20) & 7u;
        int slotv = -1;
        int c = __hip_atomic_fetch_add(&cnt[xcc], 1, __ATOMIC_RELAXED,
                                       __HIP_MEMORY_SCOPE_AGENT);
        if (c < NSLOTS) {
            if (c == NSLOTS - 1) atomicCAS(winner, -1, (int)xcc);
            int w;
            do {
                __builtin_amdgcn_s_sleep(2);
                w = __hip_atomic_load(winner, __ATOMIC_RELAXED,
                                      __HIP_MEMORY_SCOPE_AGENT);
            } while (w < 0);
            if (w == (int)xcc) slotv = c;
        }
        s_slot = slotv;
    }
    __syncthreads();
    const int slot = s_slot;
    if (slot < 0) return;            // shell WG: exit, free the CU

    const int  lane   = tid & 63;
    const int  wid    = tid >> 6;                    // 0..3
    const bool storer = ((lane & 7) == 0);
    const int  myrow  = slot * 32 + wid * 8 + (lane >> 3);

    // Poison own fast rows with sc0 stores (same scope as the hot loop),
    // then agent-scope readiness barrier before anyone polls.
    if (storer) {
        const float poison = __uint_as_float(0xAAAAAAAAu);
        asm volatile("global_store_dword %0, %1, off sc0"
                     :: "v"(fastring + myrow), "v"(poison) : "memory");
        asm volatile("global_store_dword %0, %1, off sc0"
                     :: "v"(fastring + NTAGS + myrow), "v"(poison) : "memory");
    }
    asm volatile("s_waitcnt vmcnt(0)" ::: "memory");
    __syncthreads();
    if (tid == 0) {
        __hip_atomic_fetch_add(ready, 1, __ATOMIC_RELAXED,
                               __HIP_MEMORY_SCOPE_AGENT);
        while (__hip_atomic_load(ready, __ATOMIC_RELAXED,
                                 __HIP_MEMORY_SCOPE_AGENT) < NSLOTS)
            __builtin_amdgcn_s_sleep(1);
    }
    __syncthreads();

    // ---- M fragments; v[4k+j] <-> col c = 256k + 4*lane + j ----
    const int r0row = slot * 32 + wid * 8;
    float M[8][16];
    float sm[8];
    #pragma unroll
    for (int r = 0; r < 8; ++r) {
        sm[r] = 0.0f;
        const float* tr = trans + (size_t)(r0row + r) * NTAGS;
        #pragma unroll
        for (int k = 0; k < 4; ++k)
            #pragma unroll
            for (int j = 0; j < 4; ++j) {
                const float m = __expf(tr[256 * k + 4 * lane + j]);
                M[r][4 * k + j] = m;
                sm[r] += m;
            }
    }
    const float msum = reduce8(sm, lane);

    double s2 = 0.0;
    float dbuf[8] = {}, dn[8] = {};
    if (storer) {
        #pragma unroll
        for (int i = 0; i < 8; ++i)
            dbuf[i] = decoded[(size_t)i * NTAGS + myrow];
    }

    // frontier registers (raw p values): r1 = latest label, r0 = previous
    float r1 = (myrow == START_I) ? 1.0f : 0.0f;   // label 0 (init)
    float r0 = r1;
    bool dualstore = false, troubleset = false, fastdead = false;
    int  badacq = 0;

    for (int tb = 0; tb < TSTEPS; tb += 8) {
        #pragma unroll
        for (int u = 0; u < 8; ++u) {
            const int   t   = tb + u;
            const bool  POS = (((u >> 1) & 1) == 0);
            const float sg  = POS ? 1.0f : -1.0f;

            float v[16];
            if (tb == 0 && u == 0) {
                #pragma unroll
                for (int k = 0; k < 4; ++k)
                    #pragma unroll
                    for (int j = 0; j < 4; ++j)
                        v[4*k+j] = (256*k + 4*lane + j == START_I) ? 2.0f : 1.0f;
            } else {
                const float* fsrc = fastring + (size_t)(u & 1) * NTAGS + 4 * lane;
                const u64_t* ssrc = slowring + (size_t)(u & 1) * NTAGS + 4 * lane;
                if (POS) acquire<true >(t, lane, fsrc, ssrc, slowring, myrow,
                                        storer, r1, r0, trouble, troubleset,
                                        fastdead, badacq, v);
                else     acquire<false>(t, lane, fsrc, ssrc, slowring, myrow,
                                        storer, r1, r0, trouble, troubleset,
                                        fastdead, badacq, v);
            }

            if (u == 0 && storer && tb + 8 < TSTEPS) {
                #pragma unroll
                for (int i = 0; i < 8; ++i)
                    dn[i] = decoded[(size_t)(tb + 8 + i) * NTAGS + myrow];
            }

            const float e    = __expf(dbuf[u]);
            const float Eraw = POS ? max16(v) : min16(v);

            float a[8];
            #pragma unroll
            for (int r = 0; r < 8; ++r) a[r] = 0.0f;
            #pragma unroll
            for (int r = 0; r < 8; ++r)
                #pragma unroll
                for (int j = 0; j < 16; ++j)
                    a[r] = fmaf(M[r][j], v[j], a[r]);

            float ml = fmaf(sg, Eraw, -1.0f);
            ml = fmaxf(ml, __shfl_xor(ml, 32, 64));
            ml = fmaxf(ml, __shfl_xor(ml, 16, 64));
            ml = fmaxf(ml, __shfl_xor(ml,  8, 64));
            ml = fmaxf(ml, __shfl_xor(ml,  4, 64));
            ml = fmaxf(ml, __shfl_xor(ml,  2, 64));
            ml = fmaxf(ml, __shfl_xor(ml,  1, 64));

            const float b = reduce8(a, lane);

            s2 += (double)__log2f(ml);

            if (storer) {
                const float s    = fmaf(sg, b, -msum);
                const float outv = e * s * __builtin_amdgcn_rcpf(ml);
                const float sgn  = (((u + 1) >> 1) & 1) ? -1.0f : 1.0f;
                const float sv   = fmaf(sgn, outv, sgn);     // sgn*(outv+1)
                float* fdst = fastring + (size_t)((u + 1) & 1) * NTAGS + myrow;
                asm volatile("global_store_dword %0, %1, off sc0"
                             :: "v"(fdst), "v"(sv) : "memory");
                if (dualstore || fastdead)
                    __hip_atomic_store(slowring + (size_t)((u+1) & 1) * NTAGS
                        + myrow, packts(t + 1, outv),
                        __ATOMIC_RELAXED, __HIP_MEMORY_SCOPE_AGENT);
                r0 = r1; r1 = outv;
            }

            if (!dualstore && ((t & 15) == 15)) {
                const int fl = fastdead ? 1
                    : __hip_atomic_load(trouble, __ATOMIC_RELAXED,
                                        __HIP_MEMORY_SCOPE_AGENT);
                if (fl) {
                    dualstore = true;
                    if (storer) {   // publish current frontier immediately
                        __hip_atomic_store(slowring + (size_t)((t+1) & 1) * NTAGS
                            + myrow, packts(t + 1, r1),
                            __ATOMIC_RELAXED, __HIP_MEMORY_SCOPE_AGENT);
                        __hip_atomic_store(slowring + (size_t)(t & 1) * NTAGS
                            + myrow, packts(t, r0),
                            __ATOMIC_RELAXED, __HIP_MEMORY_SCOPE_AGENT);
                    }
                }
            }
        }
        #pragma unroll
        for (int i = 0; i < 8; ++i) dbuf[i] = dn[i];
    }

    // Final publish: make the last two labels MALL-visible unconditionally.
    if (storer) {
        __hip_atomic_store(slowring + (size_t)(TSTEPS & 1) * NTAGS + myrow,
            packts(TSTEPS, r1), __ATOMIC_RELAXED, __HIP_MEMORY_SCOPE_AGENT);
        __hip_atomic_store(slowring + (size_t)((TSTEPS-1) & 1) * NTAGS + myrow,
            packts(TSTEPS - 1, r0), __ATOMIC_RELAXED, __HIP_MEMORY_SCOPE_AGENT);
    }

    // ---- epilogue: slot 0 / wave 0 folds in trans[STOP,:] ----
    if (slot == 0 && wid == 0) {
        float v[16];   // labels TSTEPS: parity 0, sign +
        acquire<true>(TSTEPS, lane, fastring + 4 * lane, slowring + 4 * lane,
                      slowring, myrow, storer, r1, r0, trouble, troubleset,
                      fastdead, badacq, v);
        float term = 0.0f;
        const float* tr = trans + (size_t)STOP_I * NTAGS;
        #pragma unroll
        for (int k = 0; k < 4; ++k)
            #pragma unroll
            for (int j = 0; j < 4; ++j)
                term = fmaf(__expf(tr[256 * k + 4 * lane + j]),
                            v[4 * k + j] - 1.0f, term);
        term += __shfl_xor(term, 32, 64);
        term += __shfl_xor(term, 16, 64);
        term += __shfl_xor(term,  8, 64);
        term += __shfl_xor(term,  4, 64);
        term += __shfl_xor(term,  2, 64);
        term += __shfl_xor(term,  1, 64);
        if (lane == 0)
            out[0] = (float)(0.6931471805599453 * (s2 + log2((double)term)));
    }
}

extern "C" void kernel_launch(void* const* d_in, const int* in_sizes, int n_in,
                              void* d_out, int out_size, void* d_ws, size_t ws_size,
                              hipStream_t stream) {
    const float* decoded = (const float*)d_in[0];   // [16384, 1024] f32
    const float* trans   = (const float*)d_in[1];   // [1024, 1024]  f32
    float* out = (float*)d_out;
    float* ws  = (float*)d_ws;
    // layout: fast f32[2][1024] | slow u64[2][1024] | cnt[8],ready,trouble,winner

    // poison both rings (slow-ring tags 0xAAAAAAAA never match a real label)
    hipMemsetAsync(ws, 0xAA, 6 * NTAGS * sizeof(float), stream);
    // cnt[8] + ready + trouble = 0 ; winner = -1
    hipMemsetAsync((char*)ws + 6 * NTAGS * sizeof(float), 0x00, 40, stream);
    hipMemsetAsync((char*)ws + 6 * NTAGS * sizeof(float) + 40, 0xFF, 4, stream);

    hipLaunchKernelGGL(crf_forward_kernel, dim3(NLAUNCH), dim3(TPB), 0, stream,
                       decoded, trans, out, ws);
}

// Round 7
// 64975.232 us; speedup vs baseline: 1.1044x; 1.1044x over previous
//
#include <hip/hip_runtime.h>
#include <math.h>

#define TSTEPS 16384
#define NTAGS  1024
#define NWG    256      // one workgroup per CU
#define TPB    128      // 2 waves; 1 wave per SIMD
#define START_I 1022
#define STOP_I  1023

// CRF forward in the linear (exp) domain, latency-optimized — R7.
//   p_{t+1} = e_t . (M p_t) / max(p_t),  S += log(max(p_t))
//   alpha   = S + log( sum_i p_T[i] * exp(trans[STOP,i]) )
// Proven R0 architecture: agent-scope depth-2 ring through the MALL, each
// wave polls the full 1024-float vector (16 values/lane, 8x u64 loads).
// Validation embedded in data: stored value = sign(t)*(p+1), sign flips
// every ring wrap; poison/stale values never validate.
//
// R7 deltas vs R0 (21.7ms):
//  1. BATCHED emission prefetch: R0 issued a stride-4KB decoded load every
//     step right before the poll; the poll's vmcnt(0) drained that ~500-900cy
//     HBM/MALL load on the critical path EVERY step. Now 8 steps of decoded
//     are fetched once per block, issued after detect (~60cy/step amortized).
//  2. tree min16/max16 (was 15 serial fminf inside the poll period).
//  3. 8x unrolled body: ring parity and signs are compile-time constants.
// (R2-R6 XCD-local arc abandoned: all store/load scope pairings failed to
// validate cross-CU, most likely a broken XCC_ID election — no way to bin
// WGs by XCD reliably from HIP here.)

typedef unsigned long long u64_t;

static __device__ __forceinline__ float min16(const float v[16]) {
    float a = fminf(v[0],  v[1]),  b = fminf(v[2],  v[3]);
    float c = fminf(v[4],  v[5]),  d = fminf(v[6],  v[7]);
    float e = fminf(v[8],  v[9]),  f = fminf(v[10], v[11]);
    float g = fminf(v[12], v[13]), h = fminf(v[14], v[15]);
    a = fminf(a, b); c = fminf(c, d); e = fminf(e, f); g = fminf(g, h);
    return fminf(fminf(a, c), fminf(e, g));
}
static __device__ __forceinline__ float max16(const float v[16]) {
    float a = fmaxf(v[0],  v[1]),  b = fmaxf(v[2],  v[3]);
    float c = fmaxf(v[4],  v[5]),  d = fmaxf(v[6],  v[7]);
    float e = fmaxf(v[8],  v[9]),  f = fmaxf(v[10], v[11]);
    float g = fmaxf(v[12], v[13]), h = fmaxf(v[14], v[15]);
    a = fmaxf(a, b); c = fmaxf(c, d); e = fmaxf(e, f); g = fmaxf(g, h);
    return fmaxf(fmaxf(a, c), fmaxf(e, g));
}

__global__ __launch_bounds__(TPB)
void crf_forward_kernel(const float* __restrict__ decoded,
                        const float* __restrict__ trans,
                        float* __restrict__ out,
                        float* __restrict__ ring)
{
    const int tid  = threadIdx.x;
    const int wg   = blockIdx.x;
    const int lane = tid & 63;
    const int wid  = tid >> 6;            // 0..1
    const int r0   = wg * 4 + wid * 2;    // this wave's two output tags
    const int r1   = r0 + 1;

    // ---- init: M fragments (cols 128k + 2*lane + h), row sums of M ----
    float Ma[16], Mb[16];
    float sma = 0.0f, smb = 0.0f;
    #pragma unroll
    for (int k = 0; k < 8; ++k) {
        const int c = 128 * k + 2 * lane;
        Ma[2*k]   = __expf(trans[(size_t)r0 * NTAGS + c]);
        Ma[2*k+1] = __expf(trans[(size_t)r0 * NTAGS + c + 1]);
        Mb[2*k]   = __expf(trans[(size_t)r1 * NTAGS + c]);
        Mb[2*k+1] = __expf(trans[(size_t)r1 * NTAGS + c + 1]);
        sma += Ma[2*k] + Ma[2*k+1];
        smb += Mb[2*k] + Mb[2*k+1];
    }
    // reduce M row sums with the SAME lane->row mapping as the step reduce
    sma += __shfl_xor(sma, 32, 64);
    smb += __shfl_xor(smb, 32, 64);
    float msum = (lane & 32) ? smb : sma;
    msum += __shfl_xor(msum, 16, 64);
    msum += __shfl_xor(msum,  8, 64);
    msum += __shfl_xor(msum,  4, 64);
    msum += __shfl_xor(msum,  2, 64);
    msum += __shfl_xor(msum,  1, 64);
    // lanes 0..31 hold sum(M[r0,:]); lanes 32..63 hold sum(M[r1,:])

    const bool storer = ((lane & 31) == 0);     // lane 0 -> r0, lane 32 -> r1
    const int  myrow  = (lane >> 5) ? r1 : r0;

    double s2 = 0.0;                 // sum of log2(max), uniform per wave
    float dbuf[8] = {}, dn[8] = {};  // emissions, batched 8 timesteps
    if (storer) {
        #pragma unroll
        for (int i = 0; i < 8; ++i)
            dbuf[i] = decoded[(size_t)i * NTAGS + myrow];
    }

    for (int tb = 0; tb < TSTEPS; tb += 8) {
        #pragma unroll
        for (int u = 0; u < 8; ++u) {
            // static per u: ring parity = u&1, sign = ((u>>1)&1) ? - : +
            const bool  POS = (((u >> 1) & 1) == 0);
            const float sg  = POS ? 1.0f : -1.0f;

            // ---- obtain raw v (stored-form) for this lane's 16 columns ----
            float v[16];
            if (tb == 0 && u == 0) {
                #pragma unroll
                for (int k = 0; k < 8; ++k) {
                    const int c = 128 * k + 2 * lane;
                    v[2*k]   = (c     == START_I) ? 2.0f : 1.0f;  // p+1, sg=+1
                    v[2*k+1] = (c + 1 == START_I) ? 2.0f : 1.0f;
                }
            } else {
                const u64_t* src =
                    (const u64_t*)(ring + (size_t)(u & 1) * NTAGS) + lane;
                #pragma unroll 1
                for (;;) {
                    u64_t q[8];
                    #pragma unroll
                    for (int k = 0; k < 8; ++k)
                        q[k] = __hip_atomic_load(src + 64 * k, __ATOMIC_RELAXED,
                                                 __HIP_MEMORY_SCOPE_AGENT);
                    #pragma unroll
                    for (int k = 0; k < 8; ++k) {
                        v[2*k]   = __uint_as_float((unsigned)q[k]);
                        v[2*k+1] = __uint_as_float((unsigned)(q[k] >> 32));
                    }
                    if (POS) { if (min16(v) >=  1.0f) break; }
                    else     { if (max16(v) <= -1.0f) break; }
                }
            }

            // batched emission prefetch for the NEXT block — issued AFTER
            // detect, once per 8 steps, so its HBM latency is drained at most
            // once per block instead of every step (R0's flaw).
            if (u == 0 && storer && tb + 8 < TSTEPS) {
                #pragma unroll
                for (int i = 0; i < 8; ++i)
                    dn[i] = decoded[(size_t)(tb + 8 + i) * NTAGS + myrow];
            }

            const float e    = __expf(dbuf[u]);          // off critical path
            const float Eraw = POS ? max16(v) : min16(v);

            // ---- dot products on raw v (sign/offset folded into msum) ----
            float a0 = 0.0f, a1 = 0.0f;
            #pragma unroll
            for (int j = 0; j < 16; ++j) {
                a0 = fmaf(Ma[j], v[j], a0);
                a1 = fmaf(Mb[j], v[j], a1);
            }

            // global max of pv across the wave (exact, associative)
            float ml = fmaf(sg, Eraw, -1.0f);
            ml = fmaxf(ml, __shfl_xor(ml, 32, 64));
            ml = fmaxf(ml, __shfl_xor(ml, 16, 64));
            ml = fmaxf(ml, __shfl_xor(ml,  8, 64));
            ml = fmaxf(ml, __shfl_xor(ml,  4, 64));
            ml = fmaxf(ml, __shfl_xor(ml,  2, 64));
            ml = fmaxf(ml, __shfl_xor(ml,  1, 64));

            // row-sum butterfly: pack two rows into the two half-waves
            a0 += __shfl_xor(a0, 32, 64);
            a1 += __shfl_xor(a1, 32, 64);
            float b = (lane & 32) ? a1 : a0;
            b += __shfl_xor(b, 16, 64);
            b += __shfl_xor(b,  8, 64);
            b += __shfl_xor(b,  4, 64);
            b += __shfl_xor(b,  2, 64);
            b += __shfl_xor(b,  1, 64);

            s2 += (double)__log2f(ml);          // off critical path

            if (storer) {
                const float s    = fmaf(sg, b, -msum);        // sum M . pv
                const float outv = e * s * __builtin_amdgcn_rcpf(ml);
                // static: store parity (u+1)&1, sign = (((u+1)>>1)&1) ? - : +
                const float sgn  = (((u + 1) >> 1) & 1) ? -1.0f : 1.0f;
                __hip_atomic_store(ring + (size_t)((u + 1) & 1) * NTAGS + myrow,
                                   fmaf(sgn, outv, sgn),      // sgn*(outv+1)
                                   __ATOMIC_RELAXED, __HIP_MEMORY_SCOPE_AGENT);
            }
        }
        #pragma unroll
        for (int i = 0; i < 8; ++i) dbuf[i] = dn[i];
    }

    // ---- epilogue: wg0/wave0 folds in trans[STOP,:] ----
    if (wg == 0 && wid == 0) {
        // p_T lives in slot (TSTEPS&1)=0 with sign +1 ((TSTEPS>>1)&1 = 0)
        const u64_t* src = (const u64_t*)ring + lane;
        float v[16];
        #pragma unroll 1
        for (;;) {
            u64_t q[8];
            #pragma unroll
            for (int k = 0; k < 8; ++k)
                q[k] = __hip_atomic_load(src + 64 * k, __ATOMIC_RELAXED,
                                         __HIP_MEMORY_SCOPE_AGENT);
            #pragma unroll
            for (int k = 0; k < 8; ++k) {
                v[2*k]   = __uint_as_float((unsigned)q[k]);
                v[2*k+1] = __uint_as_float((unsigned)(q[k] >> 32));
            }
            if (min16(v) >= 1.0f) break;
        }
        float term = 0.0f;
        #pragma unroll
        for (int k = 0; k < 8; ++k) {
            const int c = 128 * k + 2 * lane;
            term = fmaf(__expf(trans[(size_t)STOP_I * NTAGS + c]),
                        v[2*k] - 1.0f, term);
            term = fmaf(__expf(trans[(size_t)STOP_I * NTAGS + c + 1]),
                        v[2*k+1] - 1.0f, term);
        }
        term += __shfl_xor(term, 32, 64);
        term += __shfl_xor(term, 16, 64);
        term += __shfl_xor(term,  8, 64);
        term += __shfl_xor(term,  4, 64);
        term += __shfl_xor(term,  2, 64);
        term += __shfl_xor(term,  1, 64);
        if (lane == 0)
            out[0] = (float)(0.6931471805599453 * (s2 + log2((double)term)));
    }
}

extern "C" void kernel_launch(void* const* d_in, const int* in_sizes, int n_in,
                              void* d_out, int out_size, void* d_ws, size_t ws_size,
                              hipStream_t stream) {
    const float* decoded = (const float*)d_in[0];   // [16384, 1024] f32
    const float* trans   = (const float*)d_in[1];   // [1024, 1024]  f32
    float* out  = (float*)d_out;
    float* ring = (float*)d_ws;                     // 2 * 1024 floats = 8 KB

    // Ring "invalid" state independent of harness poisoning (0xAA already
    // invalid, but enforce it ourselves for replay safety).
    hipMemsetAsync(ring, 0xAA, 2 * NTAGS * sizeof(float), stream);

    hipLaunchKernelGGL(crf_forward_kernel, dim3(NWG), dim3(TPB), 0, stream,
                       decoded, trans, out, ring);
}

// Round 8
// 60922.296 us; speedup vs baseline: 1.1779x; 1.0665x over previous
//
#include <hip/hip_runtime.h>
#include <math.h>

#define TSTEPS 16384
#define NTAGS  1024
#define NWG    256      // one workgroup per CU
#define TPB    128      // 2 waves; 1 wave per SIMD
#define START_I 1022
#define STOP_I  1023

// CRF forward in the linear (exp) domain, latency-optimized — R8.
//   p_{t+1} = e_t . (M p_t) / max(p_t),  S += log(max(p_t))
//   alpha   = S + log( sum_i p_T[i] * exp(trans[STOP,i]) )
// Agent-scope depth-2 ring through the MALL; each wave polls the full
// 1024-float vector (16 values/lane, 8x u64 loads). Validation embedded in
// the data: stored value = sign(t)*(p+1), sign flips every ring wrap;
// poison/stale values never validate.
//
// R7 post-mortem: removing R0's per-step HBM-load drain made it 3x SLOWER
// (65ms) with FETCH ∝ duration — unthrottled polling congests the MALL and
// delays store visibility itself (congestion spiral). R0's per-step drain
// was an ACCIDENTAL pacing mechanism; R1 (fewer pollers, still paced) was
// neutral because pacing, not poller count, is the control variable.
//
// R8 single delta vs R7: sleep-paced polling. First sweep immediate, then
// s_sleep(1) (~64cy) after each failed sweep: ~3-5 sweeps/step instead of
// ~30, cutting MALL read pressure well below even R0's paced level while
// keeping R7's true wins (batched emission prefetch off the critical path,
// tree min/max validation, 8x unroll with static parity/sign).

typedef unsigned long long u64_t;

static __device__ __forceinline__ float min16(const float v[16]) {
    float a = fminf(v[0],  v[1]),  b = fminf(v[2],  v[3]);
    float c = fminf(v[4],  v[5]),  d = fminf(v[6],  v[7]);
    float e = fminf(v[8],  v[9]),  f = fminf(v[10], v[11]);
    float g = fminf(v[12], v[13]), h = fminf(v[14], v[15]);
    a = fminf(a, b); c = fminf(c, d); e = fminf(e, f); g = fminf(g, h);
    return fminf(fminf(a, c), fminf(e, g));
}
static __device__ __forceinline__ float max16(const float v[16]) {
    float a = fmaxf(v[0],  v[1]),  b = fmaxf(v[2],  v[3]);
    float c = fmaxf(v[4],  v[5]),  d = fmaxf(v[6],  v[7]);
    float e = fmaxf(v[8],  v[9]),  f = fmaxf(v[10], v[11]);
    float g = fmaxf(v[12], v[13]), h = fmaxf(v[14], v[15]);
    a = fmaxf(a, b); c = fmaxf(c, d); e = fmaxf(e, f); g = fmaxf(g, h);
    return fmaxf(fmaxf(a, c), fmaxf(e, g));
}

__global__ __launch_bounds__(TPB)
void crf_forward_kernel(const float* __restrict__ decoded,
                        const float* __restrict__ trans,
                        float* __restrict__ out,
                        float* __restrict__ ring)
{
    const int tid  = threadIdx.x;
    const int wg   = blockIdx.x;
    const int lane = tid & 63;
    const int wid  = tid >> 6;            // 0..1
    const int r0   = wg * 4 + wid * 2;    // this wave's two output tags
    const int r1   = r0 + 1;

    // ---- init: M fragments (cols 128k + 2*lane + h), row sums of M ----
    float Ma[16], Mb[16];
    float sma = 0.0f, smb = 0.0f;
    #pragma unroll
    for (int k = 0; k < 8; ++k) {
        const int c = 128 * k + 2 * lane;
        Ma[2*k]   = __expf(trans[(size_t)r0 * NTAGS + c]);
        Ma[2*k+1] = __expf(trans[(size_t)r0 * NTAGS + c + 1]);
        Mb[2*k]   = __expf(trans[(size_t)r1 * NTAGS + c]);
        Mb[2*k+1] = __expf(trans[(size_t)r1 * NTAGS + c + 1]);
        sma += Ma[2*k] + Ma[2*k+1];
        smb += Mb[2*k] + Mb[2*k+1];
    }
    // reduce M row sums with the SAME lane->row mapping as the step reduce
    sma += __shfl_xor(sma, 32, 64);
    smb += __shfl_xor(smb, 32, 64);
    float msum = (lane & 32) ? smb : sma;
    msum += __shfl_xor(msum, 16, 64);
    msum += __shfl_xor(msum,  8, 64);
    msum += __shfl_xor(msum,  4, 64);
    msum += __shfl_xor(msum,  2, 64);
    msum += __shfl_xor(msum,  1, 64);
    // lanes 0..31 hold sum(M[r0,:]); lanes 32..63 hold sum(M[r1,:])

    const bool storer = ((lane & 31) == 0);     // lane 0 -> r0, lane 32 -> r1
    const int  myrow  = (lane >> 5) ? r1 : r0;

    double s2 = 0.0;                 // sum of log2(max), uniform per wave
    float dbuf[8] = {}, dn[8] = {};  // emissions, batched 8 timesteps
    if (storer) {
        #pragma unroll
        for (int i = 0; i < 8; ++i)
            dbuf[i] = decoded[(size_t)i * NTAGS + myrow];
    }

    for (int tb = 0; tb < TSTEPS; tb += 8) {
        #pragma unroll
        for (int u = 0; u < 8; ++u) {
            // static per u: ring parity = u&1, sign = ((u>>1)&1) ? - : +
            const bool  POS = (((u >> 1) & 1) == 0);
            const float sg  = POS ? 1.0f : -1.0f;

            // ---- obtain raw v (stored-form) for this lane's 16 columns ----
            float v[16];
            if (tb == 0 && u == 0) {
                #pragma unroll
                for (int k = 0; k < 8; ++k) {
                    const int c = 128 * k + 2 * lane;
                    v[2*k]   = (c     == START_I) ? 2.0f : 1.0f;  // p+1, sg=+1
                    v[2*k+1] = (c + 1 == START_I) ? 2.0f : 1.0f;
                }
            } else {
                const u64_t* src =
                    (const u64_t*)(ring + (size_t)(u & 1) * NTAGS) + lane;
                #pragma unroll 1
                for (;;) {
                    u64_t q[8];
                    #pragma unroll
                    for (int k = 0; k < 8; ++k)
                        q[k] = __hip_atomic_load(src + 64 * k, __ATOMIC_RELAXED,
                                                 __HIP_MEMORY_SCOPE_AGENT);
                    #pragma unroll
                    for (int k = 0; k < 8; ++k) {
                        v[2*k]   = __uint_as_float((unsigned)q[k]);
                        v[2*k+1] = __uint_as_float((unsigned)(q[k] >> 32));
                    }
                    if (POS) { if (min16(v) >=  1.0f) break; }
                    else     { if (max16(v) <= -1.0f) break; }
                    // PACING: sleep ~64cy before re-sweeping. Uncongests the
                    // MALL so stores propagate at uncontended latency.
                    __builtin_amdgcn_s_sleep(1);
                }
            }

            // batched emission prefetch for the NEXT block — once per 8
            // steps, issued AFTER detect; its HBM latency is drained at most
            // once per block by a later poll's vmcnt(0).
            if (u == 0 && storer && tb + 8 < TSTEPS) {
                #pragma unroll
                for (int i = 0; i < 8; ++i)
                    dn[i] = decoded[(size_t)(tb + 8 + i) * NTAGS + myrow];
            }

            const float e    = __expf(dbuf[u]);          // off critical path
            const float Eraw = POS ? max16(v) : min16(v);

            // ---- dot products on raw v (sign/offset folded into msum) ----
            float a0 = 0.0f, a1 = 0.0f;
            #pragma unroll
            for (int j = 0; j < 16; ++j) {
                a0 = fmaf(Ma[j], v[j], a0);
                a1 = fmaf(Mb[j], v[j], a1);
            }

            // global max of pv across the wave (exact, associative)
            float ml = fmaf(sg, Eraw, -1.0f);
            ml = fmaxf(ml, __shfl_xor(ml, 32, 64));
            ml = fmaxf(ml, __shfl_xor(ml, 16, 64));
            ml = fmaxf(ml, __shfl_xor(ml,  8, 64));
            ml = fmaxf(ml, __shfl_xor(ml,  4, 64));
            ml = fmaxf(ml, __shfl_xor(ml,  2, 64));
            ml = fmaxf(ml, __shfl_xor(ml,  1, 64));

            // row-sum butterfly: pack two rows into the two half-waves
            a0 += __shfl_xor(a0, 32, 64);
            a1 += __shfl_xor(a1, 32, 64);
            float b = (lane & 32) ? a1 : a0;
            b += __shfl_xor(b, 16, 64);
            b += __shfl_xor(b,  8, 64);
            b += __shfl_xor(b,  4, 64);
            b += __shfl_xor(b,  2, 64);
            b += __shfl_xor(b,  1, 64);

            s2 += (double)__log2f(ml);          // off critical path

            if (storer) {
                const float s    = fmaf(sg, b, -msum);        // sum M . pv
                const float outv = e * s * __builtin_amdgcn_rcpf(ml);
                // static: store parity (u+1)&1, sign = (((u+1)>>1)&1) ? - : +
                const float sgn  = (((u + 1) >> 1) & 1) ? -1.0f : 1.0f;
                __hip_atomic_store(ring + (size_t)((u + 1) & 1) * NTAGS + myrow,
                                   fmaf(sgn, outv, sgn),      // sgn*(outv+1)
                                   __ATOMIC_RELAXED, __HIP_MEMORY_SCOPE_AGENT);
            }
        }
        #pragma unroll
        for (int i = 0; i < 8; ++i) dbuf[i] = dn[i];
    }

    // ---- epilogue: wg0/wave0 folds in trans[STOP,:] ----
    if (wg == 0 && wid == 0) {
        // p_T lives in slot (TSTEPS&1)=0 with sign +1 ((TSTEPS>>1)&1 = 0)
        const u64_t* src = (const u64_t*)ring + lane;
        float v[16];
        #pragma unroll 1
        for (;;) {
            u64_t q[8];
            #pragma unroll
            for (int k = 0; k < 8; ++k)
                q[k] = __hip_atomic_load(src + 64 * k, __ATOMIC_RELAXED,
                                         __HIP_MEMORY_SCOPE_AGENT);
            #pragma unroll
            for (int k = 0; k < 8; ++k) {
                v[2*k]   = __uint_as_float((unsigned)q[k]);
                v[2*k+1] = __uint_as_float((unsigned)(q[k] >> 32));
            }
            if (min16(v) >= 1.0f) break;
            __builtin_amdgcn_s_sleep(1);
        }
        float term = 0.0f;
        #pragma unroll
        for (int k = 0; k < 8; ++k) {
            const int c = 128 * k + 2 * lane;
            term = fmaf(__expf(trans[(size_t)STOP_I * NTAGS + c]),
                        v[2*k] - 1.0f, term);
            term = fmaf(__expf(trans[(size_t)STOP_I * NTAGS + c + 1]),
                        v[2*k+1] - 1.0f, term);
        }
        term += __shfl_xor(term, 32, 64);
        term += __shfl_xor(term, 16, 64);
        term += __shfl_xor(term,  8, 64);
        term += __shfl_xor(term,  4, 64);
        term += __shfl_xor(term,  2, 64);
        term += __shfl_xor(term,  1, 64);
        if (lane == 0)
            out[0] = (float)(0.6931471805599453 * (s2 + log2((double)term)));
    }
}

extern "C" void kernel_launch(void* const* d_in, const int* in_sizes, int n_in,
                              void* d_out, int out_size, void* d_ws, size_t ws_size,
                              hipStream_t stream) {
    const float* decoded = (const float*)d_in[0];   // [16384, 1024] f32
    const float* trans   = (const float*)d_in[1];   // [1024, 1024]  f32
    float* out  = (float*)d_out;
    float* ring = (float*)d_ws;                     // 2 * 1024 floats = 8 KB

    // Ring "invalid" state independent of harness poisoning (0xAA already
    // invalid, but enforce it ourselves for replay safety).
    hipMemsetAsync(ring, 0xAA, 2 * NTAGS * sizeof(float), stream);

    hipLaunchKernelGGL(crf_forward_kernel, dim3(NWG), dim3(TPB), 0, stream,
                       decoded, trans, out, ring);
}

// Round 9
// 22295.676 us; speedup vs baseline: 3.2185x; 2.7325x over previous
//
#include <hip/hip_runtime.h>
#include <math.h>

#define TSTEPS 16384
#define NTAGS  1024
#define NWG    256      // one workgroup per CU
#define TPB    128      // 2 waves; 1 wave per SIMD -> no issue contention
#define START_I 1022
#define STOP_I  1023

// CRF forward in the linear (exp) domain, latency-optimized — R9.
//   p_{t+1} = e_t . (M p_t) / max(p_t),  S += log(max(p_t))
//   alpha   = S + log( sum_i p_T[i] * exp(trans[STOP,i]) )
// EXACT R0 architecture (21.7ms champion): agent-scope depth-2 ring through
// the MALL; each WAVE polls the full 1024-float vector (16 values/lane,
// 8x u64 loads). Validation embedded in data: stored value = sign(t)*(p+1),
// sign flips every ring wrap; poison/stale never validate. The per-step
// decoded prefetch before the poll is kept VERBATIM — R7/R8 proved removing
// it regresses 3x (it acts as an accidental pacer of the poll loop).
//
// R9 single delta vs R0: the ring store is a fire-and-forget
// global_atomic_swap instead of a relaxed agent store. Atomics execute AT
// the coherence point (MALL): visibility coincides with arrival, skipping
// the store->writebuffer->L2->MALL propagation pipeline. Single writer per
// address; 4B atomicity and the validation scheme are unchanged.
// Pre-committed read: 16-19ms => store visibility had slack; ~unchanged =>
// visibility already floor, detection latency is next; slight regression
// possible if the atomic path is slower.

__global__ __launch_bounds__(TPB)
void crf_forward_kernel(const float* __restrict__ decoded,
                        const float* __restrict__ trans,
                        float* __restrict__ out,
                        float* __restrict__ ring)
{
    const int tid  = threadIdx.x;
    const int wg   = blockIdx.x;
    const int lane = tid & 63;
    const int wid  = tid >> 6;            // 0..1
    const int r0   = wg * 4 + wid * 2;    // this wave's two output tags
    const int r1   = r0 + 1;

    // ---- init: M fragments (cols 128k + 2*lane + h), row sums of M ----
    float Ma[16], Mb[16];
    float sma = 0.0f, smb = 0.0f;
    #pragma unroll
    for (int k = 0; k < 8; ++k) {
        const int c = 128 * k + 2 * lane;
        Ma[2*k]   = __expf(trans[(size_t)r0 * NTAGS + c]);
        Ma[2*k+1] = __expf(trans[(size_t)r0 * NTAGS + c + 1]);
        Mb[2*k]   = __expf(trans[(size_t)r1 * NTAGS + c]);
        Mb[2*k+1] = __expf(trans[(size_t)r1 * NTAGS + c + 1]);
        sma += Ma[2*k] + Ma[2*k+1];
        smb += Mb[2*k] + Mb[2*k+1];
    }
    // reduce M row sums with the SAME lane->row mapping as the step reduce
    sma += __shfl_xor(sma, 32, 64);
    smb += __shfl_xor(smb, 32, 64);
    float msum = (lane & 32) ? smb : sma;
    msum += __shfl_xor(msum, 16, 64);
    msum += __shfl_xor(msum,  8, 64);
    msum += __shfl_xor(msum,  4, 64);
    msum += __shfl_xor(msum,  2, 64);
    msum += __shfl_xor(msum,  1, 64);
    // lanes 0..31 now hold sum(M[r0,:]); lanes 32..63 hold sum(M[r1,:])

    const bool storer = ((lane & 31) == 0);     // lane 0 -> r0, lane 32 -> r1
    const int  myrow  = (lane >> 5) ? r1 : r0;

    double s2   = 0.0;    // sum of log2(max) — maintained uniformly per wave
    float dcur  = 0.0f, dnext = 0.0f;
    if (storer) dcur = decoded[myrow];          // emission for t = 0

    for (int t = 0; t < TSTEPS; ++t) {
        const float e = __expf(dcur);           // off critical path
        if (storer && (t + 1) < TSTEPS)
            dnext = decoded[(size_t)(t + 1) * NTAGS + myrow];

        const float sg = ((t >> 1) & 1) ? -1.0f : 1.0f;

        // ---- obtain raw v (stored-form) for this lane's 16 columns ----
        float v[16];
        if (t == 0) {
            #pragma unroll
            for (int k = 0; k < 8; ++k) {
                const int c = 128 * k + 2 * lane;
                v[2*k]   = (c     == START_I) ? 2.0f : 1.0f;  // pv+1, sg=+1
                v[2*k+1] = (c + 1 == START_I) ? 2.0f : 1.0f;
            }
        } else {
            const unsigned long long* src =
                (const unsigned long long*)(ring + (size_t)(t & 1) * NTAGS) + lane;
            if (sg > 0.0f) {
                for (;;) {
                    unsigned long long q[8];
                    #pragma unroll
                    for (int k = 0; k < 8; ++k)
                        q[k] = __hip_atomic_load(src + 64 * k, __ATOMIC_RELAXED,
                                                 __HIP_MEMORY_SCOPE_AGENT);
                    #pragma unroll
                    for (int k = 0; k < 8; ++k) {
                        v[2*k]   = __uint_as_float((unsigned)q[k]);
                        v[2*k+1] = __uint_as_float((unsigned)(q[k] >> 32));
                    }
                    float mn = v[0];
                    #pragma unroll
                    for (int j = 1; j < 16; ++j) mn = fminf(mn, v[j]);
                    if (mn >= 1.0f) break;      // all 16 valid
                }
            } else {
                for (;;) {
                    unsigned long long q[8];
                    #pragma unroll
                    for (int k = 0; k < 8; ++k)
                        q[k] = __hip_atomic_load(src + 64 * k, __ATOMIC_RELAXED,
                                                 __HIP_MEMORY_SCOPE_AGENT);
                    #pragma unroll
                    for (int k = 0; k < 8; ++k) {
                        v[2*k]   = __uint_as_float((unsigned)q[k]);
                        v[2*k+1] = __uint_as_float((unsigned)(q[k] >> 32));
                    }
                    float mx = v[0];
                    #pragma unroll
                    for (int j = 1; j < 16; ++j) mx = fmaxf(mx, v[j]);
                    if (mx <= -1.0f) break;
                }
            }
        }

        // ---- per-lane raw extreme (for the global max of pv) ----
        float Eraw = v[0];
        if (sg > 0.0f) {
            #pragma unroll
            for (int j = 1; j < 16; ++j) Eraw = fmaxf(Eraw, v[j]);
        } else {
            #pragma unroll
            for (int j = 1; j < 16; ++j) Eraw = fminf(Eraw, v[j]);
        }

        // ---- dot products on raw v (sign/offset folded into msum) ----
        float a0 = 0.0f, a1 = 0.0f;
        #pragma unroll
        for (int j = 0; j < 16; ++j) {
            a0 = fmaf(Ma[j], v[j], a0);
            a1 = fmaf(Mb[j], v[j], a1);
        }

        // global max of pv across the wave (exact, associative)
        float ml = fmaf(sg, Eraw, -1.0f);
        ml = fmaxf(ml, __shfl_xor(ml, 32, 64));
        ml = fmaxf(ml, __shfl_xor(ml, 16, 64));
        ml = fmaxf(ml, __shfl_xor(ml,  8, 64));
        ml = fmaxf(ml, __shfl_xor(ml,  4, 64));
        ml = fmaxf(ml, __shfl_xor(ml,  2, 64));
        ml = fmaxf(ml, __shfl_xor(ml,  1, 64));

        // row-sum butterfly: pack two rows into the two half-waves
        a0 += __shfl_xor(a0, 32, 64);
        a1 += __shfl_xor(a1, 32, 64);
        float b = (lane & 32) ? a1 : a0;
        b += __shfl_xor(b, 16, 64);
        b += __shfl_xor(b,  8, 64);
        b += __shfl_xor(b,  4, 64);
        b += __shfl_xor(b,  2, 64);
        b += __shfl_xor(b,  1, 64);

        s2 += (double)__log2f(ml);              // off critical path

        if (storer) {
            const float s    = fmaf(sg, b, -msum);            // sum M . pv
            const float outv = e * s * __builtin_amdgcn_rcpf(ml);
            const int   tn   = t + 1;
            const float sgn  = ((tn >> 1) & 1) ? -1.0f : 1.0f;
            const float sv   = fmaf(sgn, outv, sgn);          // sgn*(outv+1)
            // R9 delta: fire-and-forget atomic swap — executes AT the MALL,
            // value visible on arrival (no store->L2->MALL propagation).
            float* dst = ring + (size_t)(tn & 1) * NTAGS + myrow;
            asm volatile("global_atomic_swap %0, %1, off"
                         :: "v"(dst), "v"(sv) : "memory");
        }
        dcur = dnext;
    }

    // ---- epilogue: wg0/wave0 folds in trans[STOP,:] ----
    if (wg == 0 && wid == 0) {
        // p_T lives in slot (TSTEPS&1)=0 with sign +1 ((TSTEPS>>1)&1 = 0)
        const unsigned long long* src = (const unsigned long long*)ring + lane;
        float v[16];
        for (;;) {
            unsigned long long q[8];
            #pragma unroll
            for (int k = 0; k < 8; ++k)
                q[k] = __hip_atomic_load(src + 64 * k, __ATOMIC_RELAXED,
                                         __HIP_MEMORY_SCOPE_AGENT);
            #pragma unroll
            for (int k = 0; k < 8; ++k) {
                v[2*k]   = __uint_as_float((unsigned)q[k]);
                v[2*k+1] = __uint_as_float((unsigned)(q[k] >> 32));
            }
            float mn = v[0];
            #pragma unroll
            for (int j = 1; j < 16; ++j) mn = fminf(mn, v[j]);
            if (mn >= 1.0f) break;
        }
        float term = 0.0f;
        #pragma unroll
        for (int k = 0; k < 8; ++k) {
            const int c = 128 * k + 2 * lane;
            term = fmaf(__expf(trans[(size_t)STOP_I * NTAGS + c]),
                        v[2*k] - 1.0f, term);
            term = fmaf(__expf(trans[(size_t)STOP_I * NTAGS + c + 1]),
                        v[2*k+1] - 1.0f, term);
        }
        term += __shfl_xor(term, 32, 64);
        term += __shfl_xor(term, 16, 64);
        term += __shfl_xor(term,  8, 64);
        term += __shfl_xor(term,  4, 64);
        term += __shfl_xor(term,  2, 64);
        term += __shfl_xor(term,  1, 64);
        if (lane == 0)
            out[0] = (float)(0.6931471805599453 * (s2 + log2((double)term)));
    }
}

extern "C" void kernel_launch(void* const* d_in, const int* in_sizes, int n_in,
                              void* d_out, int out_size, void* d_ws, size_t ws_size,
                              hipStream_t stream) {
    const float* decoded = (const float*)d_in[0];   // [16384, 1024] f32
    const float* trans   = (const float*)d_in[1];   // [1024, 1024]  f32
    float* out  = (float*)d_out;
    float* ring = (float*)d_ws;                     // 2 * 1024 floats = 8 KB

    // Ring "invalid" state independent of harness poisoning (0xAA already
    // invalid, but enforce it ourselves for replay safety).
    hipMemsetAsync(ring, 0xAA, 2 * NTAGS * sizeof(float), stream);

    hipLaunchKernelGGL(crf_forward_kernel, dim3(NWG), dim3(TPB), 0, stream,
                       decoded, trans, out, ring);
}